// Round 9
// baseline (288.490 us; speedup 1.0000x reference)
//
#include <hip/hip_runtime.h>
#include <hip/hip_bf16.h>
#include <hip/hip_cooperative_groups.h>

namespace cg = cooperative_groups;

#define NN 20000
#define GG 128

typedef __bf16 bf16x8_t __attribute__((ext_vector_type(8)));
typedef float  f32x4_t  __attribute__((ext_vector_type(4)));
typedef __hip_bfloat16 hbf16;

// packed-weight table in ws (bf16-element offsets)
#define PK_NPW1 0       // 32768 : npW1 B-frags (16 ct x 4 kb x 64 lane x 8)
#define PK_PPW1 32768   // 16384 : ppW1 (8 ct x 4 kb x 64 x 8)
#define PK_NPW2 49152   //  4096 : npW2 (8 kb x 64 x 8), cols>=12 zero
#define PK_PPW2 53248   //  2048 : ppW2 (4 kb x 64 x 8), cols>=3 zero
#define PK_WN   55296   //  4096 : Wn   (8 ct x 64 x 8), K padded 12->32
#define GADD_OFF 59392  // then gadd fp32[128][128]

#define NGS 6

__device__ __forceinline__ float silu_f(float v) {
    return v * __builtin_amdgcn_rcpf(1.0f + __expf(-v));
}

// async HBM->LDS copy: per wave, nbytes/4 bytes in 1024B issues (64 x 16B)
__device__ __forceinline__ void cp_async(hbf16* dst, const hbf16* src,
                                         int nbytes, int w, int lane) {
    const int per_wave = nbytes >> 2;   // 4 waves
    const char* g = (const char*)src + w * per_wave + lane * 16;
    char* l = (char*)dst + w * per_wave + lane * 16;
    for (int j = 0; j < per_wave; j += 1024)
        __builtin_amdgcn_global_load_lds(
            (__attribute__((address_space(1))) void*)(g + j),
            (__attribute__((address_space(3))) void*)(l + j),
            16, 0, 0);
}

struct Params {
    const float *x; const int *batch;
    const float *t, *topo, *stab, *sust;
    const float *tmW1, *tmb1, *tmW2, *tmb2;
    const float *topoW1, *topob1, *topoW2, *topob2;
    const float *stabW1, *stabb1, *stabW2, *stabb2;
    const float *sustW1, *sustb1, *sustW2, *sustb2;
    const float *combW1, *combb1, *combW2, *combb2;
    const float *Wv, *Wo, *bo, *bn;
    const float *npW1, *npb1, *npW2, *npb2;
    const float *ppW1, *ppb1, *ppW2, *ppb2;
    const float *Wn;
    float *gadd; hbf16 *wsb; float *out;
};

// ---------------------------------------------------------------------------
// Single cooperative kernel, 313 blocks x 256 threads.
// Phase 1: blocks [0,128) graph gadd pipeline; [128,244) weight packing.
// grid.sync()
// Phase 2: all blocks: per-node MFMA MLPs with async dbuf weight streaming.
// MFMA contract (16x16x32 bf16), q=lane>>4, r=lane&15:
//   A[m=r][k=q*8+j]   B[k=q*8+j][n=r]   D[m=q*4+i][n=r]
// ---------------------------------------------------------------------------
__global__ __launch_bounds__(256) void mono_kernel(Params p) {
    __shared__ __align__(16) char smem[79936];

    const int tid  = threadIdx.x;
    const int b    = blockIdx.x;

    // ======================= Phase 1 =======================
    if (b >= GG && b < GG + 116) {
        // ---- weight packing: 512 slots/block
#pragma unroll
        for (int e = 0; e < 2; ++e) {
            const int s = (b - GG) * 512 + e * 256 + tid;
            if (s < 32768) {                       // npW1: [128,256]
                const int pط = s;
                const int j = pط & 7, l = (pط >> 3) & 63, kb = (pط >> 9) & 3, ct = pط >> 11;
                const int k = kb * 32 + ((l >> 4) << 3) + j;
                const int n = ct * 16 + (l & 15);
                p.wsb[PK_NPW1 + pط] = __float2bfloat16(p.npW1[k * 256 + n]);
            } else if (s < 49152) {                // ppW1: [128,128]
                const int pط = s - 32768;
                const int j = pط & 7, l = (pط >> 3) & 63, kb = (pط >> 9) & 3, ct = pط >> 11;
                const int k = kb * 32 + ((l >> 4) << 3) + j;
                const int n = ct * 16 + (l & 15);
                p.wsb[PK_PPW1 + pط] = __float2bfloat16(p.ppW1[k * 128 + n]);
            } else if (s < 53248) {                // npW2: [256,12] -> N pad 16
                const int pط = s - 49152;
                const int j = pط & 7, l = (pط >> 3) & 63, kb = pط >> 9;
                const int k = kb * 32 + ((l >> 4) << 3) + j;
                const int n = l & 15;
                p.wsb[PK_NPW2 + pط] = __float2bfloat16(n < 12 ? p.npW2[k * 12 + n] : 0.0f);
            } else if (s < 55296) {                // ppW2: [128,3] -> N pad 16
                const int pط = s - 53248;
                const int j = pط & 7, l = (pط >> 3) & 63, kb = pط >> 9;
                const int k = kb * 32 + ((l >> 4) << 3) + j;
                const int n = l & 15;
                p.wsb[PK_PPW2 + pط] = __float2bfloat16(n < 3 ? p.ppW2[k * 3 + n] : 0.0f);
            } else if (s < 59392) {                // Wn: [12,128] -> K pad 32
                const int pط = s - 55296;
                const int j = pط & 7, l = (pط >> 3) & 63, ct = pط >> 9;
                const int k = ((l >> 4) << 3) + j;
                const int n = ct * 16 + (l & 15);
                p.wsb[PK_WN + pط] = __float2bfloat16(k < 12 ? p.Wn[k * 128 + n] : 0.0f);
            }
        }
    } else if (b < GG) {
        // ---- graph gadd pipeline (256 threads)
        float* s_te  = (float*)smem;            // 128
        float* s_th1 = (float*)(smem + 512);    // 256
        float* s_tef = (float*)(smem + 1536);   // 128
        float* s_l1  = (float*)(smem + 2048);   // 64
        float* s_cat = (float*)(smem + 2304);   // 64
        float* s_c1  = (float*)(smem + 2560);   // 64
        float* s_cond= (float*)(smem + 2816);   // 64
        float* s_v   = (float*)(smem + 3072);   // 128
        float* s_red = (float*)(smem + 3584);   // 256

        const int g = b;

        if (tid < 128) {
            const float tval = p.t[g];
            const int i = tid & 63;
            const float fr = __expf(-(float)i * 0.14619587892025688f);
            const float arg = tval * fr;
            s_te[tid] = (tid < 64) ? sinf(arg) : cosf(arg);
        } else if (tid < 192) {
            const int c = tid - 128;
            if (c < 32) {
                float acc = p.topob1[c];
                for (int k = 0; k < 7; ++k)
                    acc += p.topo[g * 7 + k] * p.topoW1[k * 32 + c];
                s_l1[c] = silu_f(acc);
            } else if (c < 48) {
                const int j = c - 32;
                float acc = p.stabb1[j];
                for (int k = 0; k < 2; ++k)
                    acc += p.stab[g * 2 + k] * p.stabW1[k * 16 + j];
                s_l1[c] = silu_f(acc);
            } else {
                const int j = c - 48;
                float acc = p.sustb1[j];
                for (int k = 0; k < 3; ++k)
                    acc += p.sust[g * 3 + k] * p.sustW1[k * 16 + j];
                s_l1[c] = silu_f(acc);
            }
        }
        __syncthreads();

        // tmW1 [128]->[256]
        {
            float acc = p.tmb1[tid];
#pragma unroll 16
            for (int k = 0; k < 128; ++k)
                acc += s_te[k] * p.tmW1[k * 256 + tid];
            s_th1[tid] = silu_f(acc);
        }
        __syncthreads();

        // tmW2 [256]->[128], split-k 2
        {
            const int j = tid & 127, half = tid >> 7;
            float acc = 0.0f;
#pragma unroll 16
            for (int kk = 0; kk < 128; ++kk)
                acc += s_th1[half * 128 + kk] * p.tmW2[(half * 128 + kk) * 128 + j];
            s_red[tid] = acc;
        }
        __syncthreads();

        if (tid < 128) {
            s_tef[tid] = p.tmb2[tid] + s_red[tid] + s_red[tid + 128];
        } else if (tid < 192) {
            const int c = tid - 128;
            if (c < 32) {
                float acc = p.topob2[c];
                for (int k = 0; k < 32; ++k)
                    acc += s_l1[k] * p.topoW2[k * 32 + c];
                s_cat[c] = acc;
            } else if (c < 48) {
                const int j = c - 32;
                float acc = p.stabb2[j];
                for (int k = 0; k < 16; ++k)
                    acc += s_l1[32 + k] * p.stabW2[k * 16 + j];
                s_cat[c] = acc;
            } else {
                const int j = c - 48;
                float acc = p.sustb2[j];
                for (int k = 0; k < 16; ++k)
                    acc += s_l1[48 + k] * p.sustW2[k * 16 + j];
                s_cat[c] = acc;
            }
        }
        __syncthreads();

        // comb L1, split-k 4
        {
            const int j = tid & 63, part = tid >> 6;
            float acc = 0.0f;
#pragma unroll
            for (int kk = 0; kk < 16; ++kk)
                acc += s_cat[part * 16 + kk] * p.combW1[(part * 16 + kk) * 64 + j];
            s_red[tid] = acc;
        }
        __syncthreads();
        if (tid < 64)
            s_c1[tid] = silu_f(p.combb1[tid] + s_red[tid] + s_red[tid + 64] +
                               s_red[tid + 128] + s_red[tid + 192]);
        __syncthreads();

        // comb L2, split-k 4
        {
            const int j = tid & 63, part = tid >> 6;
            float acc = 0.0f;
#pragma unroll
            for (int kk = 0; kk < 16; ++kk)
                acc += s_c1[part * 16 + kk] * p.combW2[(part * 16 + kk) * 64 + j];
            s_red[tid] = acc;
        }
        __syncthreads();
        if (tid < 64)
            s_cond[tid] = p.combb2[tid] + s_red[tid] + s_red[tid + 64] +
                          s_red[tid + 128] + s_red[tid + 192];
        __syncthreads();

        // v = cond @ Wv, split-k 2
        {
            const int j = tid & 127, half = tid >> 7;
            float acc = 0.0f;
#pragma unroll
            for (int kk = 0; kk < 32; ++kk)
                acc += s_cond[half * 32 + kk] * p.Wv[(half * 32 + kk) * 128 + j];
            s_red[tid] = acc;
        }
        __syncthreads();
        if (tid < 128) s_v[tid] = s_red[tid] + s_red[tid + 128];
        __syncthreads();

        // a = v @ Wo ; gadd = 6*(a + bo + silu(tef))
        {
            const int j = tid & 127, half = tid >> 7;
            float acc = 0.0f;
#pragma unroll 16
            for (int kk = 0; kk < 64; ++kk)
                acc += s_v[half * 64 + kk] * p.Wo[(half * 64 + kk) * 128 + j];
            s_red[tid] = acc;
        }
        __syncthreads();
        if (tid < 128)
            p.gadd[g * 128 + tid] =
                6.0f * (p.bo[tid] + s_red[tid] + s_red[tid + 128] + silu_f(s_tef[tid]));
    }

    cg::this_grid().sync();

    // ======================= Phase 2: node MLPs =======================
    hbf16* s_wA   = (hbf16*)smem;              // 16384 B
    hbf16* s_wB   = (hbf16*)(smem + 16384);    // 16384 B
    hbf16* s_wn   = (hbf16*)(smem + 32768);    //  8192 B
    hbf16* tbuf   = (hbf16*)(smem + 40960);    // 33792 B
    float* s_gadd = (float*)(smem + 74752);    //  3072 B
    float* s_bias = (float*)(smem + 77824);    //  2112 B

    const int nb   = b * 64;
    const int w    = tid >> 6;
    const int lane = tid & 63;
    const int q    = lane >> 4;
    const int r    = lane & 15;
    const int n16  = nb + w * 16;

    hbf16* wb = tbuf + w * (16 * 264);
    const hbf16* wsb = p.wsb;
    const float* gadd = p.gadd;
    float* out = p.out;

    // ---- async staging: Wn frags + npW1 chunk0
    cp_async(s_wn, wsb + PK_WN, 8192, w, lane);
    cp_async(s_wA, wsb + PK_NPW1, 16384, w, lane);

    // ---- synchronous staged loads (drain together at S0)
    const int g0 = p.batch[nb];
    for (int i = tid; i < NGS * 128; i += 256) {
        int gr = g0 + (i >> 7);
        if (gr > GG - 1) gr = GG - 1;
        s_gadd[i] = gadd[gr * 128 + (i & 127)];
    }
    for (int i = tid; i < 528; i += 256) {
        float v;
        if (i < 128) v = p.bn[i];
        else if (i < 384) v = p.npb1[i - 128];
        else if (i < 396) v = p.npb2[i - 384];
        else if (i < 524) v = p.ppb1[i - 396];
        else if (i < 527) v = p.ppb2[i - 524];
        else v = 0.0f;
        s_bias[i] = v;
    }

    // x A-frag (M=16, K=12 padded to 32)
    bf16x8_t Ax;
    {
        const int node = n16 + r;
        float xv[8];
#pragma unroll
        for (int j = 0; j < 8; ++j) xv[j] = 0.0f;
        if (node < NN) {
            if (q == 0) {
                const float4 a = *reinterpret_cast<const float4*>(p.x + node * 12);
                const float4 c = *reinterpret_cast<const float4*>(p.x + node * 12 + 4);
                xv[0] = a.x; xv[1] = a.y; xv[2] = a.z; xv[3] = a.w;
                xv[4] = c.x; xv[5] = c.y; xv[6] = c.z; xv[7] = c.w;
            } else if (q == 1) {
                const float4 a = *reinterpret_cast<const float4*>(p.x + node * 12 + 8);
                xv[0] = a.x; xv[1] = a.y; xv[2] = a.z; xv[3] = a.w;
            }
        }
#pragma unroll
        for (int j = 0; j < 8; ++j) {
            const hbf16 tv = __float2bfloat16(xv[j]);
            Ax[j] = *reinterpret_cast<const __bf16*>(&tv);
        }
    }
    int gidx[4];
#pragma unroll
    for (int i = 0; i < 4; ++i) {
        int gn = n16 + q * 4 + i;
        if (gn > NN - 1) gn = NN - 1;
        gidx[i] = p.batch[gn] - g0;
    }
    __syncthreads();   // S0: Wn + chunk0 + gadd + biases ready

    // ---- h = x@Wn + bn + gadd  -> wb stride 136 ; Ah regs
    bf16x8_t Ah[4];
    {
        f32x4_t hacc[8];
#pragma unroll
        for (int ct = 0; ct < 8; ++ct) {
            const bf16x8_t Bf = *reinterpret_cast<const bf16x8_t*>(
                &s_wn[(ct * 64 + lane) * 8]);
            hacc[ct] = __builtin_amdgcn_mfma_f32_16x16x32_bf16(
                Ax, Bf, (f32x4_t){0.f, 0.f, 0.f, 0.f}, 0, 0, 0);
        }
#pragma unroll
        for (int ct = 0; ct < 8; ++ct) {
            const int n = ct * 16 + r;
            const float bv = s_bias[n];
#pragma unroll
            for (int i = 0; i < 4; ++i) {
                const int gi = gidx[i];
                const float ga = (gi < NGS) ? s_gadd[gi * 128 + n]
                                            : gadd[(g0 + gi) * 128 + n];
                wb[(q * 4 + i) * 136 + n] = __float2bfloat16(hacc[ct][i] + bv + ga);
            }
        }
#pragma unroll
        for (int kb = 0; kb < 4; ++kb)
            Ah[kb] = *reinterpret_cast<const bf16x8_t*>(
                &wb[r * 136 + kb * 32 + q * 8]);
    }

    auto npL1_quad = [&](int cbase, const hbf16* sw) {
#pragma unroll
        for (int ci = 0; ci < 4; ++ci) {
            f32x4_t acc = (f32x4_t){0.f, 0.f, 0.f, 0.f};
#pragma unroll
            for (int kb = 0; kb < 4; ++kb) {
                const bf16x8_t Bf = *reinterpret_cast<const bf16x8_t*>(
                    &sw[((ci * 4 + kb) * 64 + lane) * 8]);
                acc = __builtin_amdgcn_mfma_f32_16x16x32_bf16(Ah[kb], Bf, acc, 0, 0, 0);
            }
            const int col = (cbase * 4 + ci) * 16 + r;
            const float b1 = s_bias[128 + col];
#pragma unroll
            for (int i = 0; i < 4; ++i)
                wb[(q * 4 + i) * 264 + col] = __float2bfloat16(silu_f(acc[i] + b1));
        }
    };
    auto ppL1_quad = [&](int cbase, const hbf16* sw) {
#pragma unroll
        for (int ci = 0; ci < 4; ++ci) {
            f32x4_t acc = (f32x4_t){0.f, 0.f, 0.f, 0.f};
#pragma unroll
            for (int kb = 0; kb < 4; ++kb) {
                const bf16x8_t Bf = *reinterpret_cast<const bf16x8_t*>(
                    &sw[((ci * 4 + kb) * 64 + lane) * 8]);
                acc = __builtin_amdgcn_mfma_f32_16x16x32_bf16(Ah[kb], Bf, acc, 0, 0, 0);
            }
            const int col = (cbase * 4 + ci) * 16 + r;
            const float b1 = s_bias[396 + col];
#pragma unroll
            for (int i = 0; i < 4; ++i)
                wb[(q * 4 + i) * 136 + col] = __float2bfloat16(silu_f(acc[i] + b1));
        }
    };

    // ---- streamed K-loop: issue next chunk, compute current, barrier
    cp_async(s_wB, wsb + PK_NPW1 + 8192, 16384, w, lane);
    npL1_quad(0, s_wA);
    __syncthreads();

    cp_async(s_wA, wsb + PK_NPW1 + 16384, 16384, w, lane);
    npL1_quad(1, s_wB);
    __syncthreads();

    cp_async(s_wB, wsb + PK_NPW1 + 24576, 16384, w, lane);
    npL1_quad(2, s_wA);
    __syncthreads();

    cp_async(s_wA, wsb + PK_NPW2, 8192, w, lane);
    npL1_quad(3, s_wB);
    __syncthreads();

    // np L2 from A (npW2)
    cp_async(s_wB, wsb + PK_PPW1, 16384, w, lane);
    {
        f32x4_t acc2 = (f32x4_t){0.f, 0.f, 0.f, 0.f};
#pragma unroll
        for (int kb = 0; kb < 8; ++kb) {
            const bf16x8_t Af = *reinterpret_cast<const bf16x8_t*>(
                &wb[r * 264 + kb * 32 + q * 8]);
            const bf16x8_t Bf = *reinterpret_cast<const bf16x8_t*>(
                &s_wA[(kb * 64 + lane) * 8]);
            acc2 = __builtin_amdgcn_mfma_f32_16x16x32_bf16(Af, Bf, acc2, 0, 0, 0);
        }
        if (r < 12) {
            const float b2 = s_bias[384 + r];
#pragma unroll
            for (int i = 0; i < 4; ++i) {
                const int gn = n16 + q * 4 + i;
                if (gn < NN) out[gn * 12 + r] = acc2[i] + b2;
            }
        }
    }
    __syncthreads();

    cp_async(s_wA, wsb + PK_PPW1 + 8192, 16384, w, lane);
    ppL1_quad(0, s_wB);
    __syncthreads();

    cp_async(s_wB, wsb + PK_PPW2, 4096, w, lane);
    ppL1_quad(1, s_wA);
    __syncthreads();

    // pp L2 from B (ppW2)
    {
        f32x4_t acc2 = (f32x4_t){0.f, 0.f, 0.f, 0.f};
#pragma unroll
        for (int kb = 0; kb < 4; ++kb) {
            const bf16x8_t Af = *reinterpret_cast<const bf16x8_t*>(
                &wb[r * 136 + kb * 32 + q * 8]);
            const bf16x8_t Bf = *reinterpret_cast<const bf16x8_t*>(
                &s_wB[(kb * 64 + lane) * 8]);
            acc2 = __builtin_amdgcn_mfma_f32_16x16x32_bf16(Af, Bf, acc2, 0, 0, 0);
        }
        if (r < 3) {
            const float b2 = s_bias[524 + r];
#pragma unroll
            for (int i = 0; i < 4; ++i) {
                const int gn = n16 + q * 4 + i;
                if (gn < NN) out[NN * 12 + gn * 3 + r] = acc2[i] + b2;
            }
        }
    }
}

// ---------------------------------------------------------------------------
extern "C" void kernel_launch(void* const* d_in, const int* in_sizes, int n_in,
                              void* d_out, int out_size, void* d_ws, size_t ws_size,
                              hipStream_t stream) {
    Params prm;
    prm.x      = (const float*)d_in[0];
    prm.t      = (const float*)d_in[4];
    prm.topo   = (const float*)d_in[5];
    prm.stab   = (const float*)d_in[6];
    prm.sust   = (const float*)d_in[7];
    prm.batch  = (const int*)d_in[8];
    prm.Wn     = (const float*)d_in[9];
    prm.bn     = (const float*)d_in[10];
    prm.tmW1   = (const float*)d_in[13];
    prm.tmb1   = (const float*)d_in[14];
    prm.tmW2   = (const float*)d_in[15];
    prm.tmb2   = (const float*)d_in[16];
    prm.topoW1 = (const float*)d_in[17];
    prm.topob1 = (const float*)d_in[18];
    prm.topoW2 = (const float*)d_in[19];
    prm.topob2 = (const float*)d_in[20];
    prm.stabW1 = (const float*)d_in[21];
    prm.stabb1 = (const float*)d_in[22];
    prm.stabW2 = (const float*)d_in[23];
    prm.stabb2 = (const float*)d_in[24];
    prm.sustW1 = (const float*)d_in[25];
    prm.sustb1 = (const float*)d_in[26];
    prm.sustW2 = (const float*)d_in[27];
    prm.sustb2 = (const float*)d_in[28];
    prm.combW1 = (const float*)d_in[29];
    prm.combb1 = (const float*)d_in[30];
    prm.combW2 = (const float*)d_in[31];
    prm.combb2 = (const float*)d_in[32];
    prm.Wv     = (const float*)d_in[35];
    prm.Wo     = (const float*)d_in[36];
    prm.bo     = (const float*)d_in[37];
    prm.npW1   = (const float*)d_in[44];
    prm.npb1   = (const float*)d_in[45];
    prm.npW2   = (const float*)d_in[46];
    prm.npb2   = (const float*)d_in[47];
    prm.ppW1   = (const float*)d_in[48];
    prm.ppb1   = (const float*)d_in[49];
    prm.ppW2   = (const float*)d_in[50];
    prm.ppb2   = (const float*)d_in[51];

    prm.wsb  = (hbf16*)d_ws;
    prm.gadd = (float*)(prm.wsb + GADD_OFF);
    prm.out  = (float*)d_out;

    void* args[] = { &prm };
    hipLaunchCooperativeKernel((const void*)mono_kernel,
                               dim3((NN + 63) / 64), dim3(256),
                               args, 0, stream);
}

// Round 10
// 240.989 us; speedup vs baseline: 1.1971x; 1.1971x over previous
//
#include <hip/hip_runtime.h>
#include <hip/hip_bf16.h>

#define NN 20000
#define GG 128

typedef __bf16 bf16x8_t __attribute__((ext_vector_type(8)));
typedef float  f32x4_t  __attribute__((ext_vector_type(4)));
typedef __hip_bfloat16 hbf16;

// ws layout (bf16-element offsets)
#define PK_NPW1 0       // 32768 : npW1 B-frags (16 ct x 4 kb x 64 lane x 8)
#define PK_PPW1 32768   // 16384 : ppW1 (8 ct x 4 kb x 64 x 8)
#define PK_NPW2 49152   //  4096 : npW2 (8 kb x 64 x 8), cols>=12 zero
#define PK_PPW2 53248   //  2048 : ppW2 (4 kb x 64 x 8), cols>=3 zero
#define PK_WN   55296   //  4096 : Wn   (8 ct x 64 x 8), K padded 12->32
#define GADD_OFF 59392  // gadd fp32[128][128] = 32768 bf16 elems
#define FLAG_OFF 92160  // int flags[128]

#define NGS 6

__device__ __forceinline__ float silu_f(float v) {
    return v * __builtin_amdgcn_rcpf(1.0f + __expf(-v));
}

// async HBM->LDS copy: per wave, nbytes/4 bytes in 1024B issues (64 x 16B)
__device__ __forceinline__ void cp_async(hbf16* dst, const hbf16* src,
                                         int nbytes, int w, int lane) {
    const int per_wave = nbytes >> 2;   // 4 waves
    const char* g = (const char*)src + w * per_wave + lane * 16;
    char* l = (char*)dst + w * per_wave + lane * 16;
    for (int j = 0; j < per_wave; j += 1024)
        __builtin_amdgcn_global_load_lds(
            (__attribute__((address_space(1))) void*)(g + j),
            (__attribute__((address_space(3))) void*)(l + j),
            16, 0, 0);
}

// ---------------------------------------------------------------------------
// Kernel 1: pack weights into MFMA B-fragment order.  232 x 256 = 59392 slots.
// ---------------------------------------------------------------------------
__global__ __launch_bounds__(256) void pack_kernel(
        const float* __restrict__ npW1, const float* __restrict__ npW2,
        const float* __restrict__ ppW1, const float* __restrict__ ppW2,
        const float* __restrict__ Wn, hbf16* __restrict__ wsb) {
    const int s = blockIdx.x * 256 + threadIdx.x;
    if (s < 32768) {                       // npW1: [128,256]
        const int p = s;
        const int j = p & 7, l = (p >> 3) & 63, kb = (p >> 9) & 3, ct = p >> 11;
        const int k = kb * 32 + ((l >> 4) << 3) + j;
        const int n = ct * 16 + (l & 15);
        wsb[PK_NPW1 + p] = __float2bfloat16(npW1[k * 256 + n]);
    } else if (s < 49152) {                // ppW1: [128,128]
        const int p = s - 32768;
        const int j = p & 7, l = (p >> 3) & 63, kb = (p >> 9) & 3, ct = p >> 11;
        const int k = kb * 32 + ((l >> 4) << 3) + j;
        const int n = ct * 16 + (l & 15);
        wsb[PK_PPW1 + p] = __float2bfloat16(ppW1[k * 128 + n]);
    } else if (s < 53248) {                // npW2: [256,12] -> N pad 16
        const int p = s - 49152;
        const int j = p & 7, l = (p >> 3) & 63, kb = p >> 9;
        const int k = kb * 32 + ((l >> 4) << 3) + j;
        const int n = l & 15;
        wsb[PK_NPW2 + p] = __float2bfloat16(n < 12 ? npW2[k * 12 + n] : 0.0f);
    } else if (s < 55296) {                // ppW2: [128,3] -> N pad 16
        const int p = s - 53248;
        const int j = p & 7, l = (p >> 3) & 63, kb = p >> 9;
        const int k = kb * 32 + ((l >> 4) << 3) + j;
        const int n = l & 15;
        wsb[PK_PPW2 + p] = __float2bfloat16(n < 3 ? ppW2[k * 3 + n] : 0.0f);
    } else {                               // Wn: [12,128] -> K pad 32
        const int p = s - 55296;
        const int j = p & 7, l = (p >> 3) & 63, ct = p >> 9;
        const int k = ((l >> 4) << 3) + j;
        const int n = ct * 16 + (l & 15);
        wsb[PK_WN + p] = __float2bfloat16(k < 12 ? Wn[k * 128 + n] : 0.0f);
    }
}

struct Params {
    const float *x; const int *batch;
    const float *t, *topo, *stab, *sust;
    const float *tmW1, *tmb1, *tmW2, *tmb2;
    const float *topoW1, *topob1, *topoW2, *topob2;
    const float *stabW1, *stabb1, *stabW2, *stabb2;
    const float *sustW1, *sustb1, *sustW2, *sustb2;
    const float *combW1, *combb1, *combW2, *combb2;
    const float *Wv, *Wo, *bo, *bn;
    const float *npb1, *npb2, *ppb1, *ppb2;
    float *gadd; hbf16 *wsb; int *flags; float *out;
};

// ---------------------------------------------------------------------------
// Kernel 2: single regular launch, 313 blocks x 256 threads, 2 blocks/CU
// (LDS-bound) => all 313 blocks co-resident (512 slots).
// Blocks [0,128): compute gadd[g], release-store flags[g]=1.
// All blocks: node MFMA MLPs; acquire-spin only on the graphs their 64-node
// window touches (batch is sorted: 1-3 graphs).
// MFMA contract (16x16x32 bf16), q=lane>>4, r=lane&15:
//   A[m=r][k=q*8+j]   B[k=q*8+j][n=r]   D[m=q*4+i][n=r]
// ---------------------------------------------------------------------------
__global__ __launch_bounds__(256) void main_kernel(Params p) {
    __shared__ __align__(16) char smem[79936];

    const int tid = threadIdx.x;
    const int b   = blockIdx.x;

    // ======================= producer: per-graph gadd =======================
    if (b < GG) {
        float* s_te  = (float*)smem;            // 128
        float* s_th1 = (float*)(smem + 512);    // 256
        float* s_tef = (float*)(smem + 1536);   // 128
        float* s_l1  = (float*)(smem + 2048);   // 64
        float* s_cat = (float*)(smem + 2304);   // 64
        float* s_c1  = (float*)(smem + 2560);   // 64
        float* s_cond= (float*)(smem + 2816);   // 64
        float* s_v   = (float*)(smem + 3072);   // 128
        float* s_red = (float*)(smem + 3584);   // 256

        const int g = b;

        if (tid < 128) {
            const float tval = p.t[g];
            const int i = tid & 63;
            const float fr = __expf(-(float)i * 0.14619587892025688f);
            const float arg = tval * fr;
            s_te[tid] = (tid < 64) ? sinf(arg) : cosf(arg);
        } else if (tid < 192) {
            const int c = tid - 128;
            if (c < 32) {
                float acc = p.topob1[c];
                for (int k = 0; k < 7; ++k)
                    acc += p.topo[g * 7 + k] * p.topoW1[k * 32 + c];
                s_l1[c] = silu_f(acc);
            } else if (c < 48) {
                const int j = c - 32;
                float acc = p.stabb1[j];
                for (int k = 0; k < 2; ++k)
                    acc += p.stab[g * 2 + k] * p.stabW1[k * 16 + j];
                s_l1[c] = silu_f(acc);
            } else {
                const int j = c - 48;
                float acc = p.sustb1[j];
                for (int k = 0; k < 3; ++k)
                    acc += p.sust[g * 3 + k] * p.sustW1[k * 16 + j];
                s_l1[c] = silu_f(acc);
            }
        }
        __syncthreads();

        // tmW1 [128]->[256]
        {
            float acc = p.tmb1[tid];
#pragma unroll 16
            for (int k = 0; k < 128; ++k)
                acc += s_te[k] * p.tmW1[k * 256 + tid];
            s_th1[tid] = silu_f(acc);
        }
        __syncthreads();

        // tmW2 [256]->[128], split-k 2
        {
            const int j = tid & 127, half = tid >> 7;
            float acc = 0.0f;
#pragma unroll 16
            for (int kk = 0; kk < 128; ++kk)
                acc += s_th1[half * 128 + kk] * p.tmW2[(half * 128 + kk) * 128 + j];
            s_red[tid] = acc;
        }
        __syncthreads();

        if (tid < 128) {
            s_tef[tid] = p.tmb2[tid] + s_red[tid] + s_red[tid + 128];
        } else if (tid < 192) {
            const int c = tid - 128;
            if (c < 32) {
                float acc = p.topob2[c];
                for (int k = 0; k < 32; ++k)
                    acc += s_l1[k] * p.topoW2[k * 32 + c];
                s_cat[c] = acc;
            } else if (c < 48) {
                const int j = c - 32;
                float acc = p.stabb2[j];
                for (int k = 0; k < 16; ++k)
                    acc += s_l1[32 + k] * p.stabW2[k * 16 + j];
                s_cat[c] = acc;
            } else {
                const int j = c - 48;
                float acc = p.sustb2[j];
                for (int k = 0; k < 16; ++k)
                    acc += s_l1[48 + k] * p.sustW2[k * 16 + j];
                s_cat[c] = acc;
            }
        }
        __syncthreads();

        // comb L1, split-k 4
        {
            const int j = tid & 63, part = tid >> 6;
            float acc = 0.0f;
#pragma unroll
            for (int kk = 0; kk < 16; ++kk)
                acc += s_cat[part * 16 + kk] * p.combW1[(part * 16 + kk) * 64 + j];
            s_red[tid] = acc;
        }
        __syncthreads();
        if (tid < 64)
            s_c1[tid] = silu_f(p.combb1[tid] + s_red[tid] + s_red[tid + 64] +
                               s_red[tid + 128] + s_red[tid + 192]);
        __syncthreads();

        // comb L2, split-k 4
        {
            const int j = tid & 63, part = tid >> 6;
            float acc = 0.0f;
#pragma unroll
            for (int kk = 0; kk < 16; ++kk)
                acc += s_c1[part * 16 + kk] * p.combW2[(part * 16 + kk) * 64 + j];
            s_red[tid] = acc;
        }
        __syncthreads();
        if (tid < 64)
            s_cond[tid] = p.combb2[tid] + s_red[tid] + s_red[tid + 64] +
                          s_red[tid + 128] + s_red[tid + 192];
        __syncthreads();

        // v = cond @ Wv, split-k 2
        {
            const int j = tid & 127, half = tid >> 7;
            float acc = 0.0f;
#pragma unroll
            for (int kk = 0; kk < 32; ++kk)
                acc += s_cond[half * 32 + kk] * p.Wv[(half * 32 + kk) * 128 + j];
            s_red[tid] = acc;
        }
        __syncthreads();
        if (tid < 128) s_v[tid] = s_red[tid] + s_red[tid + 128];
        __syncthreads();

        // a = v @ Wo ; gadd = 6*(a + bo + silu(tef))
        {
            const int j = tid & 127, half = tid >> 7;
            float acc = 0.0f;
#pragma unroll 16
            for (int kk = 0; kk < 64; ++kk)
                acc += s_v[half * 64 + kk] * p.Wo[(half * 64 + kk) * 128 + j];
            s_red[tid] = acc;
        }
        __syncthreads();
        if (tid < 128)
            p.gadd[g * 128 + tid] =
                6.0f * (p.bo[tid] + s_red[tid] + s_red[tid + 128] + silu_f(s_tef[tid]));
        __syncthreads();
        if (tid == 0) {
            __threadfence();
            __hip_atomic_store(p.flags + g, 1, __ATOMIC_RELEASE,
                               __HIP_MEMORY_SCOPE_AGENT);
        }
        __syncthreads();   // all waves past LDS use before node phase reuses smem
    }

    // ======================= node MLPs (all blocks) =======================
    hbf16* s_wA   = (hbf16*)smem;              // 16384 B
    hbf16* s_wB   = (hbf16*)(smem + 16384);    // 16384 B
    hbf16* s_wn   = (hbf16*)(smem + 32768);    //  8192 B
    hbf16* tbuf   = (hbf16*)(smem + 40960);    // 33792 B
    float* s_gadd = (float*)(smem + 74752);    //  3072 B
    float* s_bias = (float*)(smem + 77824);    //  2112 B

    const int nb   = b * 64;
    const int w    = tid >> 6;
    const int lane = tid & 63;
    const int q    = lane >> 4;
    const int r    = lane & 15;
    const int n16  = nb + w * 16;

    hbf16* wb = tbuf + w * (16 * 264);
    const hbf16* wsb = p.wsb;
    const float* gadd = p.gadd;
    float* out = p.out;

    // ---- async staging (packed table ready: pack_kernel completed) ----
    cp_async(s_wn, wsb + PK_WN, 8192, w, lane);
    cp_async(s_wA, wsb + PK_NPW1, 16384, w, lane);

    const int g0 = p.batch[nb];
    const int nlast = (nb + 63 < NN) ? nb + 63 : NN - 1;
    const int g1 = p.batch[nlast];

    for (int i = tid; i < 528; i += 256) {
        float v;
        if (i < 128) v = p.bn[i];
        else if (i < 384) v = p.npb1[i - 128];
        else if (i < 396) v = p.npb2[i - 384];
        else if (i < 524) v = p.ppb1[i - 396];
        else if (i < 527) v = p.ppb2[i - 524];
        else v = 0.0f;
        s_bias[i] = v;
    }

    // x A-frag (M=16, K=12 padded to 32)
    bf16x8_t Ax;
    {
        const int node = n16 + r;
        float xv[8];
#pragma unroll
        for (int j = 0; j < 8; ++j) xv[j] = 0.0f;
        if (node < NN) {
            if (q == 0) {
                const float4 a = *reinterpret_cast<const float4*>(p.x + node * 12);
                const float4 c = *reinterpret_cast<const float4*>(p.x + node * 12 + 4);
                xv[0] = a.x; xv[1] = a.y; xv[2] = a.z; xv[3] = a.w;
                xv[4] = c.x; xv[5] = c.y; xv[6] = c.z; xv[7] = c.w;
            } else if (q == 1) {
                const float4 a = *reinterpret_cast<const float4*>(p.x + node * 12 + 8);
                xv[0] = a.x; xv[1] = a.y; xv[2] = a.z; xv[3] = a.w;
            }
        }
#pragma unroll
        for (int j = 0; j < 8; ++j) {
            const hbf16 tv = __float2bfloat16(xv[j]);
            Ax[j] = *reinterpret_cast<const __bf16*>(&tv);
        }
    }
    int gidx[4];
#pragma unroll
    for (int i = 0; i < 4; ++i) {
        int gn = n16 + q * 4 + i;
        if (gn > NN - 1) gn = NN - 1;
        gidx[i] = p.batch[gn] - g0;
    }

    // ---- wait for the graphs this block needs (usually 1-2) ----
    if (tid <= g1 - g0) {
        while (__hip_atomic_load(p.flags + g0 + tid, __ATOMIC_ACQUIRE,
                                 __HIP_MEMORY_SCOPE_AGENT) != 1)
            __builtin_amdgcn_s_sleep(2);
    }
    __syncthreads();   // flags observed by all threads

    // gadd rows now safe to read
    for (int i = tid; i < NGS * 128; i += 256) {
        int gr = g0 + (i >> 7);
        if (gr > GG - 1) gr = GG - 1;
        s_gadd[i] = gadd[gr * 128 + (i & 127)];
    }
    __syncthreads();   // S0: Wn + chunk0 (async) + gadd + biases ready

    // ---- h = x@Wn + bn + gadd  -> wb stride 136 ; Ah regs
    bf16x8_t Ah[4];
    {
        f32x4_t hacc[8];
#pragma unroll
        for (int ct = 0; ct < 8; ++ct) {
            const bf16x8_t Bf = *reinterpret_cast<const bf16x8_t*>(
                &s_wn[(ct * 64 + lane) * 8]);
            hacc[ct] = __builtin_amdgcn_mfma_f32_16x16x32_bf16(
                Ax, Bf, (f32x4_t){0.f, 0.f, 0.f, 0.f}, 0, 0, 0);
        }
#pragma unroll
        for (int ct = 0; ct < 8; ++ct) {
            const int n = ct * 16 + r;
            const float bv = s_bias[n];
#pragma unroll
            for (int i = 0; i < 4; ++i) {
                const int gi = gidx[i];
                const float ga = (gi < NGS) ? s_gadd[gi * 128 + n]
                                            : gadd[(g0 + gi) * 128 + n];
                wb[(q * 4 + i) * 136 + n] = __float2bfloat16(hacc[ct][i] + bv + ga);
            }
        }
#pragma unroll
        for (int kb = 0; kb < 4; ++kb)
            Ah[kb] = *reinterpret_cast<const bf16x8_t*>(
                &wb[r * 136 + kb * 32 + q * 8]);
    }

    auto npL1_quad = [&](int cbase, const hbf16* sw) {
#pragma unroll
        for (int ci = 0; ci < 4; ++ci) {
            f32x4_t acc = (f32x4_t){0.f, 0.f, 0.f, 0.f};
#pragma unroll
            for (int kb = 0; kb < 4; ++kb) {
                const bf16x8_t Bf = *reinterpret_cast<const bf16x8_t*>(
                    &sw[((ci * 4 + kb) * 64 + lane) * 8]);
                acc = __builtin_amdgcn_mfma_f32_16x16x32_bf16(Ah[kb], Bf, acc, 0, 0, 0);
            }
            const int col = (cbase * 4 + ci) * 16 + r;
            const float b1 = s_bias[128 + col];
#pragma unroll
            for (int i = 0; i < 4; ++i)
                wb[(q * 4 + i) * 264 + col] = __float2bfloat16(silu_f(acc[i] + b1));
        }
    };
    auto ppL1_quad = [&](int cbase, const hbf16* sw) {
#pragma unroll
        for (int ci = 0; ci < 4; ++ci) {
            f32x4_t acc = (f32x4_t){0.f, 0.f, 0.f, 0.f};
#pragma unroll
            for (int kb = 0; kb < 4; ++kb) {
                const bf16x8_t Bf = *reinterpret_cast<const bf16x8_t*>(
                    &sw[((ci * 4 + kb) * 64 + lane) * 8]);
                acc = __builtin_amdgcn_mfma_f32_16x16x32_bf16(Ah[kb], Bf, acc, 0, 0, 0);
            }
            const int col = (cbase * 4 + ci) * 16 + r;
            const float b1 = s_bias[396 + col];
#pragma unroll
            for (int i = 0; i < 4; ++i)
                wb[(q * 4 + i) * 136 + col] = __float2bfloat16(silu_f(acc[i] + b1));
        }
    };

    // ---- streamed K-loop: issue next chunk, compute current, barrier
    cp_async(s_wB, wsb + PK_NPW1 + 8192, 16384, w, lane);
    npL1_quad(0, s_wA);
    __syncthreads();

    cp_async(s_wA, wsb + PK_NPW1 + 16384, 16384, w, lane);
    npL1_quad(1, s_wB);
    __syncthreads();

    cp_async(s_wB, wsb + PK_NPW1 + 24576, 16384, w, lane);
    npL1_quad(2, s_wA);
    __syncthreads();

    cp_async(s_wA, wsb + PK_NPW2, 8192, w, lane);
    npL1_quad(3, s_wB);
    __syncthreads();

    // np L2 from A (npW2)
    cp_async(s_wB, wsb + PK_PPW1, 16384, w, lane);
    {
        f32x4_t acc2 = (f32x4_t){0.f, 0.f, 0.f, 0.f};
#pragma unroll
        for (int kb = 0; kb < 8; ++kb) {
            const bf16x8_t Af = *reinterpret_cast<const bf16x8_t*>(
                &wb[r * 264 + kb * 32 + q * 8]);
            const bf16x8_t Bf = *reinterpret_cast<const bf16x8_t*>(
                &s_wA[(kb * 64 + lane) * 8]);
            acc2 = __builtin_amdgcn_mfma_f32_16x16x32_bf16(Af, Bf, acc2, 0, 0, 0);
        }
        if (r < 12) {
            const float b2 = s_bias[384 + r];
#pragma unroll
            for (int i = 0; i < 4; ++i) {
                const int gn = n16 + q * 4 + i;
                if (gn < NN) out[gn * 12 + r] = acc2[i] + b2;
            }
        }
    }
    __syncthreads();

    cp_async(s_wA, wsb + PK_PPW1 + 8192, 16384, w, lane);
    ppL1_quad(0, s_wB);
    __syncthreads();

    cp_async(s_wB, wsb + PK_PPW2, 4096, w, lane);
    ppL1_quad(1, s_wA);
    __syncthreads();

    // pp L2 from B (ppW2)
    {
        f32x4_t acc2 = (f32x4_t){0.f, 0.f, 0.f, 0.f};
#pragma unroll
        for (int kb = 0; kb < 4; ++kb) {
            const bf16x8_t Af = *reinterpret_cast<const bf16x8_t*>(
                &wb[r * 136 + kb * 32 + q * 8]);
            const bf16x8_t Bf = *reinterpret_cast<const bf16x8_t*>(
                &s_wB[(kb * 64 + lane) * 8]);
            acc2 = __builtin_amdgcn_mfma_f32_16x16x32_bf16(Af, Bf, acc2, 0, 0, 0);
        }
        if (r < 3) {
            const float b2 = s_bias[524 + r];
#pragma unroll
            for (int i = 0; i < 4; ++i) {
                const int gn = n16 + q * 4 + i;
                if (gn < NN) out[NN * 12 + gn * 3 + r] = acc2[i] + b2;
            }
        }
    }
}

// ---------------------------------------------------------------------------
extern "C" void kernel_launch(void* const* d_in, const int* in_sizes, int n_in,
                              void* d_out, int out_size, void* d_ws, size_t ws_size,
                              hipStream_t stream) {
    Params prm;
    prm.x      = (const float*)d_in[0];
    prm.t      = (const float*)d_in[4];
    prm.topo   = (const float*)d_in[5];
    prm.stab   = (const float*)d_in[6];
    prm.sust   = (const float*)d_in[7];
    prm.batch  = (const int*)d_in[8];
    const float* Wn = (const float*)d_in[9];
    prm.bn     = (const float*)d_in[10];
    prm.tmW1   = (const float*)d_in[13];
    prm.tmb1   = (const float*)d_in[14];
    prm.tmW2   = (const float*)d_in[15];
    prm.tmb2   = (const float*)d_in[16];
    prm.topoW1 = (const float*)d_in[17];
    prm.topob1 = (const float*)d_in[18];
    prm.topoW2 = (const float*)d_in[19];
    prm.topob2 = (const float*)d_in[20];
    prm.stabW1 = (const float*)d_in[21];
    prm.stabb1 = (const float*)d_in[22];
    prm.stabW2 = (const float*)d_in[23];
    prm.stabb2 = (const float*)d_in[24];
    prm.sustW1 = (const float*)d_in[25];
    prm.sustb1 = (const float*)d_in[26];
    prm.sustW2 = (const float*)d_in[27];
    prm.sustb2 = (const float*)d_in[28];
    prm.combW1 = (const float*)d_in[29];
    prm.combb1 = (const float*)d_in[30];
    prm.combW2 = (const float*)d_in[31];
    prm.combb2 = (const float*)d_in[32];
    prm.Wv     = (const float*)d_in[35];
    prm.Wo     = (const float*)d_in[36];
    prm.bo     = (const float*)d_in[37];
    const float* npW1 = (const float*)d_in[44];
    prm.npb1   = (const float*)d_in[45];
    const float* npW2 = (const float*)d_in[46];
    prm.npb2   = (const float*)d_in[47];
    const float* ppW1 = (const float*)d_in[48];
    prm.ppb1   = (const float*)d_in[49];
    const float* ppW2 = (const float*)d_in[50];
    prm.ppb2   = (const float*)d_in[51];

    prm.wsb   = (hbf16*)d_ws;
    prm.gadd  = (float*)(prm.wsb + GADD_OFF);
    prm.flags = (int*)(prm.wsb + FLAG_OFF);
    prm.out   = (float*)d_out;

    pack_kernel<<<232, 256, 0, stream>>>(npW1, npW2, ppW1, ppW2, Wn, prm.wsb);

    main_kernel<<<(NN + 63) / 64, 256, 0, stream>>>(prm);
}

// Round 11
// 196.951 us; speedup vs baseline: 1.4648x; 1.2236x over previous
//
#include <hip/hip_runtime.h>
#include <hip/hip_bf16.h>

#define NN 20000
#define GG 128

typedef __bf16 bf16x8_t __attribute__((ext_vector_type(8)));
typedef float  f32x4_t  __attribute__((ext_vector_type(4)));
typedef __hip_bfloat16 hbf16;

// packed-weight table in ws (bf16-element offsets)
#define PK_NPW1 0       // 32768 : npW1 B-frags (16 ct x 4 kb x 64 lane x 8)
#define PK_PPW1 32768   // 16384 : ppW1 (8 ct x 4 kb x 64 x 8)
#define PK_NPW2 49152   //  4096 : npW2 (8 kb x 64 x 8), cols>=12 zero
#define PK_PPW2 53248   //  2048 : ppW2 (4 kb x 64 x 8), cols>=3 zero
#define PK_WN   55296   //  4096 : Wn   (8 ct x 64 x 8), K padded 12->32
#define GADD_OFF 59392  // then gadd fp32[128][128]

__device__ __forceinline__ float silu_f(float v) {
    return v * __builtin_amdgcn_rcpf(1.0f + __expf(-v));
}

// async HBM->LDS copy: per wave, nbytes/4 bytes in 1024B issues (64 x 16B)
__device__ __forceinline__ void cp_async(hbf16* dst, const hbf16* src,
                                         int nbytes, int w, int lane) {
    const int per_wave = nbytes >> 2;   // 4 waves
    const char* g = (const char*)src + w * per_wave + lane * 16;
    char* l = (char*)dst + w * per_wave + lane * 16;
    for (int j = 0; j < per_wave; j += 1024)
        __builtin_amdgcn_global_load_lds(
            (__attribute__((address_space(1))) void*)(g + j),
            (__attribute__((address_space(3))) void*)(l + j),
            16, 0, 0);
}

// ---------------------------------------------------------------------------
// Kernel 1: blocks [0,128): per-graph gadd pipeline (512 thr, deep split-k).
//           blocks [128,244): pack weights into MFMA B-fragment order.
// ---------------------------------------------------------------------------
__global__ __launch_bounds__(512) void prep_kernel(
        const float* __restrict__ t, const float* __restrict__ topo,
        const float* __restrict__ stab, const float* __restrict__ sust,
        const float* __restrict__ tmW1, const float* __restrict__ tmb1,
        const float* __restrict__ tmW2, const float* __restrict__ tmb2,
        const float* __restrict__ topoW1, const float* __restrict__ topob1,
        const float* __restrict__ topoW2, const float* __restrict__ topob2,
        const float* __restrict__ stabW1, const float* __restrict__ stabb1,
        const float* __restrict__ stabW2, const float* __restrict__ stabb2,
        const float* __restrict__ sustW1, const float* __restrict__ sustb1,
        const float* __restrict__ sustW2, const float* __restrict__ sustb2,
        const float* __restrict__ combW1, const float* __restrict__ combb1,
        const float* __restrict__ combW2, const float* __restrict__ combb2,
        const float* __restrict__ Wv, const float* __restrict__ Wo,
        const float* __restrict__ bo,
        const float* __restrict__ npW1, const float* __restrict__ npW2,
        const float* __restrict__ ppW1, const float* __restrict__ ppW2,
        const float* __restrict__ Wn,
        float* __restrict__ gadd, hbf16* __restrict__ wsb) {
    const int tid = threadIdx.x;

    if (blockIdx.x >= GG) {
        const int s = (blockIdx.x - GG) * 512 + tid;
        if (s < 32768) {                       // npW1: [128,256]
            const int p = s;
            const int j = p & 7, l = (p >> 3) & 63, kb = (p >> 9) & 3, ct = p >> 11;
            const int k = kb * 32 + ((l >> 4) << 3) + j;
            const int n = ct * 16 + (l & 15);
            wsb[PK_NPW1 + p] = __float2bfloat16(npW1[k * 256 + n]);
        } else if (s < 49152) {                // ppW1: [128,128]
            const int p = s - 32768;
            const int j = p & 7, l = (p >> 3) & 63, kb = (p >> 9) & 3, ct = p >> 11;
            const int k = kb * 32 + ((l >> 4) << 3) + j;
            const int n = ct * 16 + (l & 15);
            wsb[PK_PPW1 + p] = __float2bfloat16(ppW1[k * 128 + n]);
        } else if (s < 53248) {                // npW2: [256,12] -> N padded 16
            const int p = s - 49152;
            const int j = p & 7, l = (p >> 3) & 63, kb = p >> 9;
            const int k = kb * 32 + ((l >> 4) << 3) + j;
            const int n = l & 15;
            wsb[PK_NPW2 + p] = __float2bfloat16(n < 12 ? npW2[k * 12 + n] : 0.0f);
        } else if (s < 55296) {                // ppW2: [128,3] -> N padded 16
            const int p = s - 53248;
            const int j = p & 7, l = (p >> 3) & 63, kb = p >> 9;
            const int k = kb * 32 + ((l >> 4) << 3) + j;
            const int n = l & 15;
            wsb[PK_PPW2 + p] = __float2bfloat16(n < 3 ? ppW2[k * 3 + n] : 0.0f);
        } else if (s < 59392) {                // Wn: [12,128] -> K padded 32
            const int p = s - 55296;
            const int j = p & 7, l = (p >> 3) & 63, ct = p >> 9;
            const int k = ((l >> 4) << 3) + j;
            const int n = ct * 16 + (l & 15);
            wsb[PK_WN + p] = __float2bfloat16(k < 12 ? Wn[k * 128 + n] : 0.0f);
        }
        return;
    }

    __shared__ float s_te[128];
    __shared__ float s_th1[256];
    __shared__ float s_tef[128];
    __shared__ float s_l1[64];
    __shared__ float s_cat[64];
    __shared__ float s_c1[64];
    __shared__ float s_cond[64];
    __shared__ float s_v[128];
    __shared__ float s_red[512];

    const int g = blockIdx.x;

    if (tid < 128) {
        const float tval = t[g];
        const int i = tid & 63;
        const float fr = __expf(-(float)i * 0.14619587892025688f);
        const float arg = tval * fr;
        s_te[tid] = (tid < 64) ? sinf(arg) : cosf(arg);
    } else if (tid < 192) {
        const int c = tid - 128;
        if (c < 32) {
            float acc = topob1[c];
            for (int k = 0; k < 7; ++k)
                acc += topo[g * 7 + k] * topoW1[k * 32 + c];
            s_l1[c] = silu_f(acc);
        } else if (c < 48) {
            const int j = c - 32;
            float acc = stabb1[j];
            for (int k = 0; k < 2; ++k)
                acc += stab[g * 2 + k] * stabW1[k * 16 + j];
            s_l1[c] = silu_f(acc);
        } else {
            const int j = c - 48;
            float acc = sustb1[j];
            for (int k = 0; k < 3; ++k)
                acc += sust[g * 3 + k] * sustW1[k * 16 + j];
            s_l1[c] = silu_f(acc);
        }
    }
    __syncthreads();

    // tmW1 [128]->[256]: split-k 2
    {
        const int col = tid & 255, half = tid >> 8;
        float acc = 0.0f;
#pragma unroll 32
        for (int kk = 0; kk < 64; ++kk) {
            const int k = half * 64 + kk;
            acc += s_te[k] * tmW1[k * 256 + col];
        }
        s_red[half * 256 + col] = acc;
    }
    __syncthreads();
    if (tid < 256)
        s_th1[tid] = silu_f(tmb1[tid] + s_red[tid] + s_red[256 + tid]);
    __syncthreads();

    // tmW2 [256]->[128]: split-k 4
    {
        const int col = tid & 127, qt = tid >> 7;
        float acc = 0.0f;
#pragma unroll 32
        for (int kk = 0; kk < 64; ++kk) {
            const int k = qt * 64 + kk;
            acc += s_th1[k] * tmW2[k * 128 + col];
        }
        s_red[qt * 128 + col] = acc;
    }
    __syncthreads();
    if (tid < 128) {
        s_tef[tid] = tmb2[tid] + s_red[tid] + s_red[128 + tid] +
                     s_red[256 + tid] + s_red[384 + tid];
    } else if (tid < 192) {
        const int c = tid - 128;
        if (c < 32) {
            float acc = topob2[c];
            for (int k = 0; k < 32; ++k)
                acc += s_l1[k] * topoW2[k * 32 + c];
            s_cat[c] = acc;
        } else if (c < 48) {
            const int j = c - 32;
            float acc = stabb2[j];
            for (int k = 0; k < 16; ++k)
                acc += s_l1[32 + k] * stabW2[k * 16 + j];
            s_cat[c] = acc;
        } else {
            const int j = c - 48;
            float acc = sustb2[j];
            for (int k = 0; k < 16; ++k)
                acc += s_l1[48 + k] * sustW2[k * 16 + j];
            s_cat[c] = acc;
        }
    }
    __syncthreads();

    // comb L1: split-k 8
    {
        const int col = tid & 63, part = tid >> 6;
        float acc = 0.0f;
#pragma unroll
        for (int kk = 0; kk < 8; ++kk) {
            const int k = part * 8 + kk;
            acc += s_cat[k] * combW1[k * 64 + col];
        }
        s_red[part * 64 + col] = acc;
    }
    __syncthreads();
    if (tid < 64) {
        float a = combb1[tid];
#pragma unroll
        for (int p = 0; p < 8; ++p) a += s_red[p * 64 + tid];
        s_c1[tid] = silu_f(a);
    }
    __syncthreads();

    // comb L2: split-k 8
    {
        const int col = tid & 63, part = tid >> 6;
        float acc = 0.0f;
#pragma unroll
        for (int kk = 0; kk < 8; ++kk) {
            const int k = part * 8 + kk;
            acc += s_c1[k] * combW2[k * 64 + col];
        }
        s_red[part * 64 + col] = acc;
    }
    __syncthreads();
    if (tid < 64) {
        float a = combb2[tid];
#pragma unroll
        for (int p = 0; p < 8; ++p) a += s_red[p * 64 + tid];
        s_cond[tid] = a;
    }
    __syncthreads();

    // v = cond @ Wv: split-k 4
    {
        const int col = tid & 127, qt = tid >> 7;
        float acc = 0.0f;
#pragma unroll
        for (int kk = 0; kk < 16; ++kk) {
            const int k = qt * 16 + kk;
            acc += s_cond[k] * Wv[k * 128 + col];
        }
        s_red[qt * 128 + col] = acc;
    }
    __syncthreads();
    if (tid < 128)
        s_v[tid] = s_red[tid] + s_red[128 + tid] + s_red[256 + tid] + s_red[384 + tid];
    __syncthreads();

    // a = v @ Wo: split-k 4 ; gadd = 6*(a + bo + silu(tef))
    {
        const int col = tid & 127, qt = tid >> 7;
        float acc = 0.0f;
#pragma unroll 32
        for (int kk = 0; kk < 32; ++kk) {
            const int k = qt * 32 + kk;
            acc += s_v[k] * Wo[k * 128 + col];
        }
        s_red[qt * 128 + col] = acc;
    }
    __syncthreads();
    if (tid < 128)
        gadd[g * 128 + tid] = 6.0f * (bo[tid] + s_red[tid] + s_red[128 + tid] +
                                      s_red[256 + tid] + s_red[384 + tid] +
                                      silu_f(s_tef[tid]));
}

// ---------------------------------------------------------------------------
// Kernel 2: per-node MLPs; weights streamed HBM->LDS via global_load_lds with
// double-buffered 16KB chunks overlapped with MFMA.  64 nodes/block, 4 waves.
// MFMA contract (16x16x32 bf16), q=lane>>4, r=lane&15:
//   A[m=r][k=q*8+j]   B[k=q*8+j][n=r]   D[m=q*4+i][n=r]
// ---------------------------------------------------------------------------
#define NGS 6

__global__ __launch_bounds__(256) void node_kernel(
        const float* __restrict__ x, const int* __restrict__ batch,
        const float* __restrict__ bn,
        const float* __restrict__ npb1, const float* __restrict__ npb2,
        const float* __restrict__ ppb1, const float* __restrict__ ppb2,
        const float* __restrict__ gadd, const hbf16* __restrict__ wsb,
        float* __restrict__ out) {
    __shared__ __align__(16) hbf16 s_wA[8192];           // 16 KB
    __shared__ __align__(16) hbf16 s_wB[8192];           // 16 KB
    __shared__ __align__(16) hbf16 s_wn[4096];           // 8 KB (Wn frags)
    __shared__ __align__(16) hbf16 tbuf[4 * 16 * 264];   // 33 KB h/z1/z2
    __shared__ float s_gadd[NGS * 128];                  // 3 KB
    __shared__ float s_bias[528];                        // 2.1 KB

    const int tid  = threadIdx.x;
    const int nb   = blockIdx.x * 64;
    const int w    = tid >> 6;
    const int lane = tid & 63;
    const int q    = lane >> 4;
    const int r    = lane & 15;
    const int n16  = nb + w * 16;

    hbf16* wb = tbuf + w * (16 * 264);

    // ---- async staging: Wn frags + npW1 chunk0
    cp_async(s_wn, wsb + PK_WN, 8192, w, lane);
    cp_async(s_wA, wsb + PK_NPW1, 16384, w, lane);

    // ---- regular staged loads (drain together at S0)
    const int g0 = batch[nb];
    for (int i = tid; i < NGS * 128; i += 256) {
        int gr = g0 + (i >> 7);
        if (gr > GG - 1) gr = GG - 1;
        s_gadd[i] = gadd[gr * 128 + (i & 127)];
    }
    // biases: 528 floats — full coverage strided loop
    for (int i = tid; i < 528; i += 256) {
        float v;
        if (i < 128) v = bn[i];
        else if (i < 384) v = npb1[i - 128];
        else if (i < 396) v = npb2[i - 384];
        else if (i < 524) v = ppb1[i - 396];
        else if (i < 527) v = ppb2[i - 524];
        else v = 0.0f;
        s_bias[i] = v;
    }

    // x A-frag (M=16, K=12 padded to 32)
    bf16x8_t Ax;
    {
        const int node = n16 + r;
        float xv[8];
#pragma unroll
        for (int j = 0; j < 8; ++j) xv[j] = 0.0f;
        if (node < NN) {
            if (q == 0) {
                const float4 a = *reinterpret_cast<const float4*>(x + node * 12);
                const float4 b = *reinterpret_cast<const float4*>(x + node * 12 + 4);
                xv[0] = a.x; xv[1] = a.y; xv[2] = a.z; xv[3] = a.w;
                xv[4] = b.x; xv[5] = b.y; xv[6] = b.z; xv[7] = b.w;
            } else if (q == 1) {
                const float4 a = *reinterpret_cast<const float4*>(x + node * 12 + 8);
                xv[0] = a.x; xv[1] = a.y; xv[2] = a.z; xv[3] = a.w;
            }
        }
#pragma unroll
        for (int j = 0; j < 8; ++j) {
            const hbf16 tv = __float2bfloat16(xv[j]);
            Ax[j] = *reinterpret_cast<const __bf16*>(&tv);
        }
    }
    int gidx[4];
#pragma unroll
    for (int i = 0; i < 4; ++i) {
        int gn = n16 + q * 4 + i;
        if (gn > NN - 1) gn = NN - 1;
        gidx[i] = batch[gn] - g0;
    }
    __syncthreads();   // S0: Wn + chunk0 + gadd + biases ready

    // ---- h = x@Wn + bn + gadd  -> wb stride 136 ; Ah regs
    bf16x8_t Ah[4];
    {
        f32x4_t hacc[8];
#pragma unroll
        for (int ct = 0; ct < 8; ++ct) {
            const bf16x8_t Bf = *reinterpret_cast<const bf16x8_t*>(
                &s_wn[(ct * 64 + lane) * 8]);
            hacc[ct] = __builtin_amdgcn_mfma_f32_16x16x32_bf16(
                Ax, Bf, (f32x4_t){0.f, 0.f, 0.f, 0.f}, 0, 0, 0);
        }
#pragma unroll
        for (int ct = 0; ct < 8; ++ct) {
            const int n = ct * 16 + r;
            const float bv = s_bias[n];
#pragma unroll
            for (int i = 0; i < 4; ++i) {
                const int gi = gidx[i];
                const float ga = (gi < NGS) ? s_gadd[gi * 128 + n]
                                            : gadd[(g0 + gi) * 128 + n];
                wb[(q * 4 + i) * 136 + n] = __float2bfloat16(hacc[ct][i] + bv + ga);
            }
        }
#pragma unroll
        for (int kb = 0; kb < 4; ++kb)
            Ah[kb] = *reinterpret_cast<const bf16x8_t*>(
                &wb[r * 136 + kb * 32 + q * 8]);
    }

    auto npL1_quad = [&](int cbase, const hbf16* sw) {
#pragma unroll
        for (int ci = 0; ci < 4; ++ci) {
            f32x4_t acc = (f32x4_t){0.f, 0.f, 0.f, 0.f};
#pragma unroll
            for (int kb = 0; kb < 4; ++kb) {
                const bf16x8_t Bf = *reinterpret_cast<const bf16x8_t*>(
                    &sw[((ci * 4 + kb) * 64 + lane) * 8]);
                acc = __builtin_amdgcn_mfma_f32_16x16x32_bf16(Ah[kb], Bf, acc, 0, 0, 0);
            }
            const int col = (cbase * 4 + ci) * 16 + r;
            const float b1 = s_bias[128 + col];
#pragma unroll
            for (int i = 0; i < 4; ++i)
                wb[(q * 4 + i) * 264 + col] = __float2bfloat16(silu_f(acc[i] + b1));
        }
    };
    auto ppL1_quad = [&](int cbase, const hbf16* sw) {
#pragma unroll
        for (int ci = 0; ci < 4; ++ci) {
            f32x4_t acc = (f32x4_t){0.f, 0.f, 0.f, 0.f};
#pragma unroll
            for (int kb = 0; kb < 4; ++kb) {
                const bf16x8_t Bf = *reinterpret_cast<const bf16x8_t*>(
                    &sw[((ci * 4 + kb) * 64 + lane) * 8]);
                acc = __builtin_amdgcn_mfma_f32_16x16x32_bf16(Ah[kb], Bf, acc, 0, 0, 0);
            }
            const int col = (cbase * 4 + ci) * 16 + r;
            const float b1 = s_bias[396 + col];
#pragma unroll
            for (int i = 0; i < 4; ++i)
                wb[(q * 4 + i) * 136 + col] = __float2bfloat16(silu_f(acc[i] + b1));
        }
    };

    // ---- streamed K-loop: issue next chunk, compute current, barrier
    cp_async(s_wB, wsb + PK_NPW1 + 8192, 16384, w, lane);
    npL1_quad(0, s_wA);
    __syncthreads();

    cp_async(s_wA, wsb + PK_NPW1 + 16384, 16384, w, lane);
    npL1_quad(1, s_wB);
    __syncthreads();

    cp_async(s_wB, wsb + PK_NPW1 + 24576, 16384, w, lane);
    npL1_quad(2, s_wA);
    __syncthreads();

    cp_async(s_wA, wsb + PK_NPW2, 8192, w, lane);
    npL1_quad(3, s_wB);
    __syncthreads();

    // np L2 from A (npW2)
    cp_async(s_wB, wsb + PK_PPW1, 16384, w, lane);
    {
        f32x4_t acc2 = (f32x4_t){0.f, 0.f, 0.f, 0.f};
#pragma unroll
        for (int kb = 0; kb < 8; ++kb) {
            const bf16x8_t Af = *reinterpret_cast<const bf16x8_t*>(
                &wb[r * 264 + kb * 32 + q * 8]);
            const bf16x8_t Bf = *reinterpret_cast<const bf16x8_t*>(
                &s_wA[(kb * 64 + lane) * 8]);
            acc2 = __builtin_amdgcn_mfma_f32_16x16x32_bf16(Af, Bf, acc2, 0, 0, 0);
        }
        if (r < 12) {
            const float b2 = s_bias[384 + r];
#pragma unroll
            for (int i = 0; i < 4; ++i) {
                const int gn = n16 + q * 4 + i;
                if (gn < NN) out[gn * 12 + r] = acc2[i] + b2;
            }
        }
    }
    __syncthreads();

    cp_async(s_wA, wsb + PK_PPW1 + 8192, 16384, w, lane);
    ppL1_quad(0, s_wB);
    __syncthreads();

    cp_async(s_wB, wsb + PK_PPW2, 4096, w, lane);
    ppL1_quad(1, s_wA);
    __syncthreads();

    // pp L2 from B (ppW2)
    {
        f32x4_t acc2 = (f32x4_t){0.f, 0.f, 0.f, 0.f};
#pragma unroll
        for (int kb = 0; kb < 4; ++kb) {
            const bf16x8_t Af = *reinterpret_cast<const bf16x8_t*>(
                &wb[r * 136 + kb * 32 + q * 8]);
            const bf16x8_t Bf = *reinterpret_cast<const bf16x8_t*>(
                &s_wB[(kb * 64 + lane) * 8]);
            acc2 = __builtin_amdgcn_mfma_f32_16x16x32_bf16(Af, Bf, acc2, 0, 0, 0);
        }
        if (r < 3) {
            const float b2 = s_bias[524 + r];
#pragma unroll
            for (int i = 0; i < 4; ++i) {
                const int gn = n16 + q * 4 + i;
                if (gn < NN) out[NN * 12 + gn * 3 + r] = acc2[i] + b2;
            }
        }
    }
}

// ---------------------------------------------------------------------------
extern "C" void kernel_launch(void* const* d_in, const int* in_sizes, int n_in,
                              void* d_out, int out_size, void* d_ws, size_t ws_size,
                              hipStream_t stream) {
    const float* x      = (const float*)d_in[0];
    const float* t      = (const float*)d_in[4];
    const float* topo   = (const float*)d_in[5];
    const float* stab   = (const float*)d_in[6];
    const float* sust   = (const float*)d_in[7];
    const int*   batch  = (const int*)d_in[8];
    const float* Wn     = (const float*)d_in[9];
    const float* bn     = (const float*)d_in[10];
    const float* tmW1   = (const float*)d_in[13];
    const float* tmb1   = (const float*)d_in[14];
    const float* tmW2   = (const float*)d_in[15];
    const float* tmb2   = (const float*)d_in[16];
    const float* topoW1 = (const float*)d_in[17];
    const float* topob1 = (const float*)d_in[18];
    const float* topoW2 = (const float*)d_in[19];
    const float* topob2 = (const float*)d_in[20];
    const float* stabW1 = (const float*)d_in[21];
    const float* stabb1 = (const float*)d_in[22];
    const float* stabW2 = (const float*)d_in[23];
    const float* stabb2 = (const float*)d_in[24];
    const float* sustW1 = (const float*)d_in[25];
    const float* sustb1 = (const float*)d_in[26];
    const float* sustW2 = (const float*)d_in[27];
    const float* sustb2 = (const float*)d_in[28];
    const float* combW1 = (const float*)d_in[29];
    const float* combb1 = (const float*)d_in[30];
    const float* combW2 = (const float*)d_in[31];
    const float* combb2 = (const float*)d_in[32];
    const float* Wv     = (const float*)d_in[35];
    const float* Wo     = (const float*)d_in[36];
    const float* bo     = (const float*)d_in[37];
    const float* npW1   = (const float*)d_in[44];
    const float* npb1   = (const float*)d_in[45];
    const float* npW2   = (const float*)d_in[46];
    const float* npb2   = (const float*)d_in[47];
    const float* ppW1   = (const float*)d_in[48];
    const float* ppb1   = (const float*)d_in[49];
    const float* ppW2   = (const float*)d_in[50];
    const float* ppb2   = (const float*)d_in[51];

    hbf16* wsb = (hbf16*)d_ws;
    float* gadd = (float*)(wsb + GADD_OFF);
    float* out = (float*)d_out;

    prep_kernel<<<GG + 116, 512, 0, stream>>>(
        t, topo, stab, sust,
        tmW1, tmb1, tmW2, tmb2,
        topoW1, topob1, topoW2, topob2,
        stabW1, stabb1, stabW2, stabb2,
        sustW1, sustb1, sustW2, sustb2,
        combW1, combb1, combW2, combb2,
        Wv, Wo, bo,
        npW1, npW2, ppW1, ppW2, Wn,
        gadd, wsb);

    node_kernel<<<(NN + 63) / 64, 256, 0, stream>>>(
        x, batch, bn, npb1, npb2, ppb1, ppb2, gadd, wsb, out);
}

// Round 12
// 193.660 us; speedup vs baseline: 1.4897x; 1.0170x over previous
//
#include <hip/hip_runtime.h>
#include <hip/hip_bf16.h>

#define NN 20000
#define GG 128
#define NTILES 313

typedef __bf16 bf16x8_t __attribute__((ext_vector_type(8)));
typedef float  f32x4_t  __attribute__((ext_vector_type(4)));
typedef __hip_bfloat16 hbf16;

// packed-weight table in ws (bf16-element offsets) — 59392 elems = 118784 B
#define PK_NPW1 0       // 32768 : npW1 B-frags (16 ct x 4 kb x 64 lane x 8)
#define PK_PPW1 32768   // 16384 : ppW1 (8 ct x 4 kb x 64 x 8)
#define PK_NPW2 49152   //  4096 : npW2 (8 kb x 64 x 8), cols>=12 zero
#define PK_PPW2 53248   //  2048 : ppW2 (4 kb x 64 x 8), cols>=3 zero
#define PK_WN   55296   //  4096 : Wn   (8 ct x 64 x 8), K padded 12->32
#define GADD_OFF 59392  // then gadd fp32[128][128]

__device__ __forceinline__ float silu_f(float v) {
    return v * __builtin_amdgcn_rcpf(1.0f + __expf(-v));
}

// async HBM->LDS copy: per wave, nbytes/4 bytes in 1024B issues (64 x 16B)
__device__ __forceinline__ void cp_async(hbf16* dst, const hbf16* src,
                                         int nbytes, int w, int lane) {
    const int per_wave = nbytes >> 2;   // 4 waves
    const char* g = (const char*)src + w * per_wave + lane * 16;
    char* l = (char*)dst + w * per_wave + lane * 16;
    for (int j = 0; j < per_wave; j += 1024)
        __builtin_amdgcn_global_load_lds(
            (__attribute__((address_space(1))) void*)(g + j),
            (__attribute__((address_space(3))) void*)(l + j),
            16, 0, 0);
}

// ---------------------------------------------------------------------------
// Kernel 1: blocks [0,128): per-graph gadd pipeline (512 thr, deep split-k).
//           blocks [128,244): pack weights into MFMA B-fragment order.
// (unchanged from the proven r8/r11 version)
// ---------------------------------------------------------------------------
__global__ __launch_bounds__(512) void prep_kernel(
        const float* __restrict__ t, const float* __restrict__ topo,
        const float* __restrict__ stab, const float* __restrict__ sust,
        const float* __restrict__ tmW1, const float* __restrict__ tmb1,
        const float* __restrict__ tmW2, const float* __restrict__ tmb2,
        const float* __restrict__ topoW1, const float* __restrict__ topob1,
        const float* __restrict__ topoW2, const float* __restrict__ topob2,
        const float* __restrict__ stabW1, const float* __restrict__ stabb1,
        const float* __restrict__ stabW2, const float* __restrict__ stabb2,
        const float* __restrict__ sustW1, const float* __restrict__ sustb1,
        const float* __restrict__ sustW2, const float* __restrict__ sustb2,
        const float* __restrict__ combW1, const float* __restrict__ combb1,
        const float* __restrict__ combW2, const float* __restrict__ combb2,
        const float* __restrict__ Wv, const float* __restrict__ Wo,
        const float* __restrict__ bo,
        const float* __restrict__ npW1, const float* __restrict__ npW2,
        const float* __restrict__ ppW1, const float* __restrict__ ppW2,
        const float* __restrict__ Wn,
        float* __restrict__ gadd, hbf16* __restrict__ wsb) {
    const int tid = threadIdx.x;

    if (blockIdx.x >= GG) {
        const int s = (blockIdx.x - GG) * 512 + tid;
        if (s < 32768) {                       // npW1: [128,256]
            const int p = s;
            const int j = p & 7, l = (p >> 3) & 63, kb = (p >> 9) & 3, ct = p >> 11;
            const int k = kb * 32 + ((l >> 4) << 3) + j;
            const int n = ct * 16 + (l & 15);
            wsb[PK_NPW1 + p] = __float2bfloat16(npW1[k * 256 + n]);
        } else if (s < 49152) {                // ppW1: [128,128]
            const int p = s - 32768;
            const int j = p & 7, l = (p >> 3) & 63, kb = (p >> 9) & 3, ct = p >> 11;
            const int k = kb * 32 + ((l >> 4) << 3) + j;
            const int n = ct * 16 + (l & 15);
            wsb[PK_PPW1 + p] = __float2bfloat16(ppW1[k * 128 + n]);
        } else if (s < 53248) {                // npW2: [256,12] -> N padded 16
            const int p = s - 49152;
            const int j = p & 7, l = (p >> 3) & 63, kb = p >> 9;
            const int k = kb * 32 + ((l >> 4) << 3) + j;
            const int n = l & 15;
            wsb[PK_NPW2 + p] = __float2bfloat16(n < 12 ? npW2[k * 12 + n] : 0.0f);
        } else if (s < 55296) {                // ppW2: [128,3] -> N padded 16
            const int p = s - 53248;
            const int j = p & 7, l = (p >> 3) & 63, kb = p >> 9;
            const int k = kb * 32 + ((l >> 4) << 3) + j;
            const int n = l & 15;
            wsb[PK_PPW2 + p] = __float2bfloat16(n < 3 ? ppW2[k * 3 + n] : 0.0f);
        } else if (s < 59392) {                // Wn: [12,128] -> K padded 32
            const int p = s - 55296;
            const int j = p & 7, l = (p >> 3) & 63, ct = p >> 9;
            const int k = ((l >> 4) << 3) + j;
            const int n = ct * 16 + (l & 15);
            wsb[PK_WN + p] = __float2bfloat16(k < 12 ? Wn[k * 128 + n] : 0.0f);
        }
        return;
    }

    __shared__ float s_te[128];
    __shared__ float s_th1[256];
    __shared__ float s_tef[128];
    __shared__ float s_l1[64];
    __shared__ float s_cat[64];
    __shared__ float s_c1[64];
    __shared__ float s_cond[64];
    __shared__ float s_v[128];
    __shared__ float s_red[512];

    const int g = blockIdx.x;

    if (tid < 128) {
        const float tval = t[g];
        const int i = tid & 63;
        const float fr = __expf(-(float)i * 0.14619587892025688f);
        const float arg = tval * fr;
        s_te[tid] = (tid < 64) ? sinf(arg) : cosf(arg);
    } else if (tid < 192) {
        const int c = tid - 128;
        if (c < 32) {
            float acc = topob1[c];
            for (int k = 0; k < 7; ++k)
                acc += topo[g * 7 + k] * topoW1[k * 32 + c];
            s_l1[c] = silu_f(acc);
        } else if (c < 48) {
            const int j = c - 32;
            float acc = stabb1[j];
            for (int k = 0; k < 2; ++k)
                acc += stab[g * 2 + k] * stabW1[k * 16 + j];
            s_l1[c] = silu_f(acc);
        } else {
            const int j = c - 48;
            float acc = sustb1[j];
            for (int k = 0; k < 3; ++k)
                acc += sust[g * 3 + k] * sustW1[k * 16 + j];
            s_l1[c] = silu_f(acc);
        }
    }
    __syncthreads();

    // tmW1 [128]->[256]: split-k 2
    {
        const int col = tid & 255, half = tid >> 8;
        float acc = 0.0f;
#pragma unroll 32
        for (int kk = 0; kk < 64; ++kk) {
            const int k = half * 64 + kk;
            acc += s_te[k] * tmW1[k * 256 + col];
        }
        s_red[half * 256 + col] = acc;
    }
    __syncthreads();
    if (tid < 256)
        s_th1[tid] = silu_f(tmb1[tid] + s_red[tid] + s_red[256 + tid]);
    __syncthreads();

    // tmW2 [256]->[128]: split-k 4
    {
        const int col = tid & 127, qt = tid >> 7;
        float acc = 0.0f;
#pragma unroll 32
        for (int kk = 0; kk < 64; ++kk) {
            const int k = qt * 64 + kk;
            acc += s_th1[k] * tmW2[k * 128 + col];
        }
        s_red[qt * 128 + col] = acc;
    }
    __syncthreads();
    if (tid < 128) {
        s_tef[tid] = tmb2[tid] + s_red[tid] + s_red[128 + tid] +
                     s_red[256 + tid] + s_red[384 + tid];
    } else if (tid < 192) {
        const int c = tid - 128;
        if (c < 32) {
            float acc = topob2[c];
            for (int k = 0; k < 32; ++k)
                acc += s_l1[k] * topoW2[k * 32 + c];
            s_cat[c] = acc;
        } else if (c < 48) {
            const int j = c - 32;
            float acc = stabb2[j];
            for (int k = 0; k < 16; ++k)
                acc += s_l1[32 + k] * stabW2[k * 16 + j];
            s_cat[c] = acc;
        } else {
            const int j = c - 48;
            float acc = sustb2[j];
            for (int k = 0; k < 16; ++k)
                acc += s_l1[48 + k] * sustW2[k * 16 + j];
            s_cat[c] = acc;
        }
    }
    __syncthreads();

    // comb L1: split-k 8
    {
        const int col = tid & 63, part = tid >> 6;
        float acc = 0.0f;
#pragma unroll
        for (int kk = 0; kk < 8; ++kk) {
            const int k = part * 8 + kk;
            acc += s_cat[k] * combW1[k * 64 + col];
        }
        s_red[part * 64 + col] = acc;
    }
    __syncthreads();
    if (tid < 64) {
        float a = combb1[tid];
#pragma unroll
        for (int p = 0; p < 8; ++p) a += s_red[p * 64 + tid];
        s_c1[tid] = silu_f(a);
    }
    __syncthreads();

    // comb L2: split-k 8
    {
        const int col = tid & 63, part = tid >> 6;
        float acc = 0.0f;
#pragma unroll
        for (int kk = 0; kk < 8; ++kk) {
            const int k = part * 8 + kk;
            acc += s_c1[k] * combW2[k * 64 + col];
        }
        s_red[part * 64 + col] = acc;
    }
    __syncthreads();
    if (tid < 64) {
        float a = combb2[tid];
#pragma unroll
        for (int p = 0; p < 8; ++p) a += s_red[p * 64 + tid];
        s_cond[tid] = a;
    }
    __syncthreads();

    // v = cond @ Wv: split-k 4
    {
        const int col = tid & 127, qt = tid >> 7;
        float acc = 0.0f;
#pragma unroll
        for (int kk = 0; kk < 16; ++kk) {
            const int k = qt * 16 + kk;
            acc += s_cond[k] * Wv[k * 128 + col];
        }
        s_red[qt * 128 + col] = acc;
    }
    __syncthreads();
    if (tid < 128)
        s_v[tid] = s_red[tid] + s_red[128 + tid] + s_red[256 + tid] + s_red[384 + tid];
    __syncthreads();

    // a = v @ Wo: split-k 4 ; gadd = 6*(a + bo + silu(tef))
    {
        const int col = tid & 127, qt = tid >> 7;
        float acc = 0.0f;
#pragma unroll 32
        for (int kk = 0; kk < 32; ++kk) {
            const int k = qt * 32 + kk;
            acc += s_v[k] * Wo[k * 128 + col];
        }
        s_red[qt * 128 + col] = acc;
    }
    __syncthreads();
    if (tid < 128)
        gadd[g * 128 + tid] = 6.0f * (bo[tid] + s_red[tid] + s_red[128 + tid] +
                                      s_red[256 + tid] + s_red[384 + tid] +
                                      silu_f(s_tef[tid]));
}

// ---------------------------------------------------------------------------
// Kernel 2: persistent per-node MLPs.  256 blocks x 256 threads (1 block/CU).
// The ENTIRE 116KB packed weight table is staged into LDS with one async
// burst (29 global_load_lds issues/wave) + ONE barrier; zero mid-kernel
// barriers after that (tbuf is wave-private; gadd prefetched to registers).
// Block b processes node-tile b and (if b<57) tile b+256, reusing the
// resident weights for the second tile at zero staging cost.
// MFMA contract (16x16x32 bf16), q=lane>>4, r=lane&15:
//   A[m=r][k=q*8+j]   B[k=q*8+j][n=r]   D[m=q*4+i][n=r]
// ---------------------------------------------------------------------------
__global__ __launch_bounds__(256, 1) void node_kernel(
        const float* __restrict__ x, const int* __restrict__ batch,
        const float* __restrict__ bn,
        const float* __restrict__ npb1, const float* __restrict__ npb2,
        const float* __restrict__ ppb1, const float* __restrict__ ppb2,
        const float* __restrict__ gadd, const hbf16* __restrict__ wsb,
        float* __restrict__ out) {
    __shared__ __align__(16) hbf16 s_wtab[59392];        // 118784 B: full table
    __shared__ __align__(16) hbf16 tbuf[4 * 16 * 264];   //  33792 B: h/z1/z2
    __shared__ float s_bias[528];                        //   2112 B

    const int tid  = threadIdx.x;
    const int w    = tid >> 6;
    const int lane = tid & 63;
    const int q    = lane >> 4;
    const int r    = lane & 15;

    hbf16* wb = tbuf + w * (16 * 264);

    // ---- one-shot async staging of the whole packed weight table
    cp_async(s_wtab, wsb, 118784, w, lane);

    // ---- biases (global->LDS, drained at S0)
    for (int i = tid; i < 528; i += 256) {
        float v;
        if (i < 128) v = bn[i];
        else if (i < 384) v = npb1[i - 128];
        else if (i < 396) v = npb2[i - 384];
        else if (i < 524) v = ppb1[i - 396];
        else if (i < 527) v = ppb2[i - 524];
        else v = 0.0f;
        s_bias[i] = v;
    }

    // per-tile register prefetch: x A-frag + gadd values
    auto prefetch = [&](int nb, bf16x8_t& Ax, float (*gv)[4]) {
        const int n16 = nb + w * 16;
        const int node = n16 + r;
        float xv[8];
#pragma unroll
        for (int j = 0; j < 8; ++j) xv[j] = 0.0f;
        if (node < NN) {
            if (q == 0) {
                const float4 a = *reinterpret_cast<const float4*>(x + node * 12);
                const float4 b = *reinterpret_cast<const float4*>(x + node * 12 + 4);
                xv[0] = a.x; xv[1] = a.y; xv[2] = a.z; xv[3] = a.w;
                xv[4] = b.x; xv[5] = b.y; xv[6] = b.z; xv[7] = b.w;
            } else if (q == 1) {
                const float4 a = *reinterpret_cast<const float4*>(x + node * 12 + 8);
                xv[0] = a.x; xv[1] = a.y; xv[2] = a.z; xv[3] = a.w;
            }
        }
#pragma unroll
        for (int j = 0; j < 8; ++j) {
            const hbf16 tv = __float2bfloat16(xv[j]);
            Ax[j] = *reinterpret_cast<const __bf16*>(&tv);
        }
        int gi[4];
#pragma unroll
        for (int i = 0; i < 4; ++i) {
            int gn = n16 + q * 4 + i;
            if (gn > NN - 1) gn = NN - 1;
            gi[i] = batch[gn];
        }
#pragma unroll
        for (int ct = 0; ct < 8; ++ct)
#pragma unroll
            for (int i = 0; i < 4; ++i)
                gv[ct][i] = gadd[gi[i] * 128 + ct * 16 + r];
    };

    // tile compute (no barriers: all LDS traffic is wave-private after S0)
    auto run_tile = [&](int nb, bf16x8_t Ax, float (*gv)[4]) {
        const int n16 = nb + w * 16;

        // h = x@Wn + bn + gadd  -> wb stride 136 ; Ah regs
        bf16x8_t Ah[4];
        {
            f32x4_t hacc[8];
#pragma unroll
            for (int ct = 0; ct < 8; ++ct) {
                const bf16x8_t Bf = *reinterpret_cast<const bf16x8_t*>(
                    &s_wtab[PK_WN + (ct * 64 + lane) * 8]);
                hacc[ct] = __builtin_amdgcn_mfma_f32_16x16x32_bf16(
                    Ax, Bf, (f32x4_t){0.f, 0.f, 0.f, 0.f}, 0, 0, 0);
            }
#pragma unroll
            for (int ct = 0; ct < 8; ++ct) {
                const int n = ct * 16 + r;
                const float bv = s_bias[n];
#pragma unroll
                for (int i = 0; i < 4; ++i)
                    wb[(q * 4 + i) * 136 + n] =
                        __float2bfloat16(hacc[ct][i] + bv + gv[ct][i]);
            }
#pragma unroll
            for (int kb = 0; kb < 4; ++kb)
                Ah[kb] = *reinterpret_cast<const bf16x8_t*>(
                    &wb[r * 136 + kb * 32 + q * 8]);
        }

        // np L1: z1 = silu(h @ npW1 + npb1)  (16 column tiles)
#pragma unroll
        for (int ct = 0; ct < 16; ++ct) {
            f32x4_t acc = (f32x4_t){0.f, 0.f, 0.f, 0.f};
#pragma unroll
            for (int kb = 0; kb < 4; ++kb) {
                const bf16x8_t Bf = *reinterpret_cast<const bf16x8_t*>(
                    &s_wtab[PK_NPW1 + ((ct * 4 + kb) * 64 + lane) * 8]);
                acc = __builtin_amdgcn_mfma_f32_16x16x32_bf16(Ah[kb], Bf, acc, 0, 0, 0);
            }
            const int col = ct * 16 + r;
            const float b1 = s_bias[128 + col];
#pragma unroll
            for (int i = 0; i < 4; ++i)
                wb[(q * 4 + i) * 264 + col] = __float2bfloat16(silu_f(acc[i] + b1));
        }

        // np L2: node_pred = z1 @ npW2 + npb2
        {
            f32x4_t acc2 = (f32x4_t){0.f, 0.f, 0.f, 0.f};
#pragma unroll
            for (int kb = 0; kb < 8; ++kb) {
                const bf16x8_t Af = *reinterpret_cast<const bf16x8_t*>(
                    &wb[r * 264 + kb * 32 + q * 8]);
                const bf16x8_t Bf = *reinterpret_cast<const bf16x8_t*>(
                    &s_wtab[PK_NPW2 + (kb * 64 + lane) * 8]);
                acc2 = __builtin_amdgcn_mfma_f32_16x16x32_bf16(Af, Bf, acc2, 0, 0, 0);
            }
            if (r < 12) {
                const float b2 = s_bias[384 + r];
#pragma unroll
                for (int i = 0; i < 4; ++i) {
                    const int gn = n16 + q * 4 + i;
                    if (gn < NN) out[gn * 12 + r] = acc2[i] + b2;
                }
            }
        }

        // pp L1: z2 = silu(h @ ppW1 + ppb1)  (8 column tiles, overwrite wb@136)
#pragma unroll
        for (int ct = 0; ct < 8; ++ct) {
            f32x4_t acc = (f32x4_t){0.f, 0.f, 0.f, 0.f};
#pragma unroll
            for (int kb = 0; kb < 4; ++kb) {
                const bf16x8_t Bf = *reinterpret_cast<const bf16x8_t*>(
                    &s_wtab[PK_PPW1 + ((ct * 4 + kb) * 64 + lane) * 8]);
                acc = __builtin_amdgcn_mfma_f32_16x16x32_bf16(Ah[kb], Bf, acc, 0, 0, 0);
            }
            const int col = ct * 16 + r;
            const float b1 = s_bias[396 + col];
#pragma unroll
            for (int i = 0; i < 4; ++i)
                wb[(q * 4 + i) * 136 + col] = __float2bfloat16(silu_f(acc[i] + b1));
        }

        // pp L2: pos_pred = z2 @ ppW2 + ppb2
        {
            f32x4_t acc2 = (f32x4_t){0.f, 0.f, 0.f, 0.f};
#pragma unroll
            for (int kb = 0; kb < 4; ++kb) {
                const bf16x8_t Af = *reinterpret_cast<const bf16x8_t*>(
                    &wb[r * 136 + kb * 32 + q * 8]);
                const bf16x8_t Bf = *reinterpret_cast<const bf16x8_t*>(
                    &s_wtab[PK_PPW2 + (kb * 64 + lane) * 8]);
                acc2 = __builtin_amdgcn_mfma_f32_16x16x32_bf16(Af, Bf, acc2, 0, 0, 0);
            }
            if (r < 3) {
                const float b2 = s_bias[524 + r];
#pragma unroll
                for (int i = 0; i < 4; ++i) {
                    const int gn = n16 + q * 4 + i;
                    if (gn < NN) out[NN * 12 + gn * 3 + r] = acc2[i] + b2;
                }
            }
        }
    };

    // ---- tile 1 prefetch (overlaps the async table staging)
    bf16x8_t Ax1;
    float gv1[8][4];
    prefetch(blockIdx.x * 64, Ax1, gv1);

    __syncthreads();   // S0: full weight table + biases resident

    const int t2 = blockIdx.x + 256;
    if (t2 < NTILES) {
        // issue tile-2 prefetch now; its loads overlap tile-1 compute
        bf16x8_t Ax2;
        float gv2[8][4];
        prefetch(t2 * 64, Ax2, gv2);
        run_tile(blockIdx.x * 64, Ax1, gv1);
        run_tile(t2 * 64, Ax2, gv2);
    } else {
        run_tile(blockIdx.x * 64, Ax1, gv1);
    }
}

// ---------------------------------------------------------------------------
extern "C" void kernel_launch(void* const* d_in, const int* in_sizes, int n_in,
                              void* d_out, int out_size, void* d_ws, size_t ws_size,
                              hipStream_t stream) {
    const float* x      = (const float*)d_in[0];
    const float* t      = (const float*)d_in[4];
    const float* topo   = (const float*)d_in[5];
    const float* stab   = (const float*)d_in[6];
    const float* sust   = (const float*)d_in[7];
    const int*   batch  = (const int*)d_in[8];
    const float* Wn     = (const float*)d_in[9];
    const float* bn     = (const float*)d_in[10];
    const float* tmW1   = (const float*)d_in[13];
    const float* tmb1   = (const float*)d_in[14];
    const float* tmW2   = (const float*)d_in[15];
    const float* tmb2   = (const float*)d_in[16];
    const float* topoW1 = (const float*)d_in[17];
    const float* topob1 = (const float*)d_in[18];
    const float* topoW2 = (const float*)d_in[19];
    const float* topob2 = (const float*)d_in[20];
    const float* stabW1 = (const float*)d_in[21];
    const float* stabb1 = (const float*)d_in[22];
    const float* stabW2 = (const float*)d_in[23];
    const float* stabb2 = (const float*)d_in[24];
    const float* sustW1 = (const float*)d_in[25];
    const float* sustb1 = (const float*)d_in[26];
    const float* sustW2 = (const float*)d_in[27];
    const float* sustb2 = (const float*)d_in[28];
    const float* combW1 = (const float*)d_in[29];
    const float* combb1 = (const float*)d_in[30];
    const float* combW2 = (const float*)d_in[31];
    const float* combb2 = (const float*)d_in[32];
    const float* Wv     = (const float*)d_in[35];
    const float* Wo     = (const float*)d_in[36];
    const float* bo     = (const float*)d_in[37];
    const float* npW1   = (const float*)d_in[44];
    const float* npb1   = (const float*)d_in[45];
    const float* npW2   = (const float*)d_in[46];
    const float* npb2   = (const float*)d_in[47];
    const float* ppW1   = (const float*)d_in[48];
    const float* ppb1   = (const float*)d_in[49];
    const float* ppW2   = (const float*)d_in[50];
    const float* ppb2   = (const float*)d_in[51];

    hbf16* wsb = (hbf16*)d_ws;
    float* gadd = (float*)(wsb + GADD_OFF);
    float* out = (float*)d_out;

    prep_kernel<<<GG + 116, 512, 0, stream>>>(
        t, topo, stab, sust,
        tmW1, tmb1, tmW2, tmb2,
        topoW1, topob1, topoW2, topob2,
        stabW1, stabb1, stabW2, stabb2,
        sustW1, sustb1, sustW2, sustb2,
        combW1, combb1, combW2, combb2,
        Wv, Wo, bo,
        npW1, npW2, ppW1, ppW2, Wn,
        gadd, wsb);

    node_kernel<<<256, 256, 0, stream>>>(
        x, batch, bn, npb1, npb2, ppb1, ppb2, gadd, wsb, out);
}